// Round 1
// baseline (537.964 us; speedup 1.0000x reference)
//
#include <hip/hip_runtime.h>
#include <math.h>

#define THRESH    0.5f
#define NEG_POSK  3
#define EPSf      1e-6f
#define CCLS      81
#define TILEA     64

__device__ __forceinline__ float iou_xy(float ax0, float ay0, float ax1, float ay1,
                                        float bx0, float by0, float bx1, float by1) {
    float lx = fmaxf(ax0, bx0), ly = fmaxf(ay0, by0);
    float rx = fminf(ax1, bx1), ry = fminf(ay1, by1);
    float w = fmaxf(rx - lx, 0.f), h = fmaxf(ry - ly, 0.f);
    float inter = w * h;
    float aa = (ax1 - ax0) * (ay1 - ay0);
    float ab = (bx1 - bx0) * (by1 - by0);
    return inter / (aa + ab - inter);
}

// ---------------- kernel 1: per-anchor best object (argmax over O, first-max) ----
__global__ void k_anchor_best(const float* __restrict__ boxes,   // [B,O,4] xyxy
                              const float* __restrict__ dboxes,  // [N,4] cxcywh
                              float* __restrict__ best_iou, int* __restrict__ best_obj,
                              int B, int N, int O) {
    int b = blockIdx.y;
    int n = blockIdx.x * blockDim.x + threadIdx.x;
    __shared__ float sb[64];  // up to O=16 boxes * 4
    if (threadIdx.x < O * 4) sb[threadIdx.x] = boxes[(size_t)b * O * 4 + threadIdx.x];
    __syncthreads();
    if (n >= N) return;
    float4 d = ((const float4*)dboxes)[n];
    float dx0 = d.x - d.z * 0.5f, dy0 = d.y - d.w * 0.5f;
    float dx1 = d.x + d.z * 0.5f, dy1 = d.y + d.w * 0.5f;
    float best = -1.f; int bo = 0;
    for (int o = 0; o < O; ++o) {
        float iou = iou_xy(sb[o*4], sb[o*4+1], sb[o*4+2], sb[o*4+3], dx0, dy0, dx1, dy1);
        if (iou > best) { best = iou; bo = o; }   // strict > keeps first index (JAX argmax)
    }
    size_t idx = (size_t)b * N + n;
    best_iou[idx] = best;
    best_obj[idx] = bo;
}

// ---------------- kernel 2: per-object best anchor (argmax over N, first-max) ----
__global__ void k_object_best(const float* __restrict__ boxes,
                              const float* __restrict__ dboxes,
                              int* __restrict__ defbox_object,
                              int B, int N, int O) {
    int bo = blockIdx.x;
    int b = bo / O, o = bo % O;
    float ax0 = boxes[((size_t)b * O + o) * 4 + 0];
    float ay0 = boxes[((size_t)b * O + o) * 4 + 1];
    float ax1 = boxes[((size_t)b * O + o) * 4 + 2];
    float ay1 = boxes[((size_t)b * O + o) * 4 + 3];
    float best = -1.f; int bi = 0x7FFFFFFF;
    for (int n = threadIdx.x; n < N; n += blockDim.x) {
        float4 d = ((const float4*)dboxes)[n];
        float dx0 = d.x - d.z * 0.5f, dy0 = d.y - d.w * 0.5f;
        float dx1 = d.x + d.z * 0.5f, dy1 = d.y + d.w * 0.5f;
        float iou = iou_xy(ax0, ay0, ax1, ay1, dx0, dy0, dx1, dy1);
        if (iou > best) { best = iou; bi = n; }   // ascending n + strict > = first max
    }
    __shared__ float sv[256];
    __shared__ int   si[256];
    sv[threadIdx.x] = best; si[threadIdx.x] = bi;
    __syncthreads();
    for (int s = 128; s > 0; s >>= 1) {
        if (threadIdx.x < s) {
            float v2 = sv[threadIdx.x + s]; int i2 = si[threadIdx.x + s];
            if (v2 > sv[threadIdx.x] || (v2 == sv[threadIdx.x] && i2 < si[threadIdx.x])) {
                sv[threadIdx.x] = v2; si[threadIdx.x] = i2;
            }
        }
        __syncthreads();
    }
    if (threadIdx.x == 0) defbox_object[bo] = si[0];
}

// ---------------- kernel 3: forced assignment (sequential per batch, last wins) ----
__global__ void k_force(const int* __restrict__ defbox_object,
                        float* __restrict__ best_iou, int* __restrict__ best_obj,
                        int B, int N, int O) {
    int b = blockIdx.x * blockDim.x + threadIdx.x;
    if (b >= B) return;
    for (int o = 0; o < O; ++o) {
        int n = defbox_object[b * O + o];
        best_obj[(size_t)b * N + n] = o;
        best_iou[(size_t)b * N + n] = 1.0f;
    }
}

// ---------------- kernel 4: labels, pos count, smooth-L1 loc loss ----------------
__global__ void k_label_loc(const float* __restrict__ boxes,
                            const float* __restrict__ dboxes,
                            const int* __restrict__ labels,
                            const float* __restrict__ locs_pred,
                            const float* __restrict__ best_iou,
                            const int* __restrict__ best_obj,
                            int* __restrict__ t_label,
                            int* __restrict__ n_pos, float* __restrict__ loc_sum,
                            int B, int N, int O) {
    int b = blockIdx.y;
    int n = blockIdx.x * blockDim.x + threadIdx.x;
    float lsum = 0.f; int cnt = 0;
    if (n < N) {
        size_t idx = (size_t)b * N + n;
        int o = best_obj[idx];
        float iou = best_iou[idx];
        int lbl = (iou < THRESH) ? 0 : labels[b * O + o];
        t_label[idx] = lbl;
        if (lbl != 0) {
            cnt = 1;
            float bx0 = boxes[((size_t)b*O+o)*4+0], by0 = boxes[((size_t)b*O+o)*4+1];
            float bx1 = boxes[((size_t)b*O+o)*4+2], by1 = boxes[((size_t)b*O+o)*4+3];
            float bcx = (bx0 + bx1) * 0.5f, bcy = (by0 + by1) * 0.5f;
            float bw = bx1 - bx0, bh = by1 - by0;
            float4 d = ((const float4*)dboxes)[n];   // cxcywh
            float t0 = (bcx - d.x) / (d.z / 10.0f + EPSf);
            float t1 = (bcy - d.y) / (d.w / 10.0f + EPSf);
            float t2 = logf(bw / d.z + EPSf) * 5.0f;
            float t3 = logf(bh / d.w + EPSf) * 5.0f;
            float4 p = ((const float4*)locs_pred)[idx];
            float dd;
            dd = fabsf(p.x - t0); lsum += (dd < 1.f) ? 0.5f*dd*dd : dd - 0.5f;
            dd = fabsf(p.y - t1); lsum += (dd < 1.f) ? 0.5f*dd*dd : dd - 0.5f;
            dd = fabsf(p.z - t2); lsum += (dd < 1.f) ? 0.5f*dd*dd : dd - 0.5f;
            dd = fabsf(p.w - t3); lsum += (dd < 1.f) ? 0.5f*dd*dd : dd - 0.5f;
        }
    }
    for (int d = 1; d < 64; d <<= 1) {
        lsum += __shfl_xor(lsum, d);
        cnt  += __shfl_xor(cnt, d);
    }
    if ((threadIdx.x & 63) == 0) {
        if (cnt)         atomicAdd(&n_pos[b], cnt);
        if (lsum != 0.f) atomicAdd(loc_sum, lsum);
    }
}

// ---------------- kernel 5: per-anchor CE (the 254 MB streaming kernel) -----------
__global__ __launch_bounds__(256) void k_conf(const float* __restrict__ cls,
                                              const int* __restrict__ t_label,
                                              float* __restrict__ vneg,
                                              float* __restrict__ pos_conf,
                                              int B, int N) {
    __shared__ __align__(16) float sm[TILEA * CCLS];   // 20736 floats = 20.7 KB
    int b = blockIdx.y;
    int a0 = blockIdx.x * TILEA;
    int valid = min(TILEA, N - a0);
    int len = valid * CCLS;
    const float* g = cls + ((size_t)b * N + a0) * CCLS;
    // coalesced stage to LDS (base is 16B-aligned when (b*N+a0)*C % 4 == 0)
    if (((((size_t)b * N + a0) * CCLS) & 3) == 0) {
        int nvec = len >> 2;
        for (int iv = threadIdx.x; iv < nvec; iv += 256)
            ((float4*)sm)[iv] = ((const float4*)g)[iv];
        for (int i = (nvec << 2) + threadIdx.x; i < len; i += 256) sm[i] = g[i];
    } else {
        for (int i = threadIdx.x; i < len; i += 256) sm[i] = g[i];
    }
    __syncthreads();

    int a = threadIdx.x >> 2, p = threadIdx.x & 3;   // 4 lanes per anchor
    bool active = (a < valid);
    int start = p * 20, cntc = (p == 3) ? 21 : 20;
    float m = -INFINITY;
    if (active) {
        const float* row = &sm[a * CCLS];
        for (int i = 0; i < cntc; ++i) m = fmaxf(m, row[start + i]);
    }
    m = fmaxf(m, __shfl_xor(m, 1));
    m = fmaxf(m, __shfl_xor(m, 2));
    float s = 0.f;
    if (active) {
        const float* row = &sm[a * CCLS];
        for (int i = 0; i < cntc; ++i) s += expf(row[start + i] - m);
    }
    s += __shfl_xor(s, 1);
    s += __shfl_xor(s, 2);
    float contrib = 0.f;
    if (active && p == 0) {
        int ag = a0 + a;
        int lbl = t_label[(size_t)b * N + ag];
        float conf = m + logf(s) - sm[a * CCLS + lbl];
        bool pos = (lbl != 0);
        vneg[(size_t)b * N + ag] = pos ? 0.f : conf;
        contrib = pos ? conf : 0.f;
    }
    for (int d = 1; d < 64; d <<= 1) contrib += __shfl_xor(contrib, d);
    if ((threadIdx.x & 63) == 0 && contrib != 0.f) atomicAdd(pos_conf, contrib);
}

// ---------------- kernel 6: exact top-k sum of negatives per batch ---------------
__device__ void wave_select(const int* hist, int nbins, int k, int* out_bin, int* out_k) {
    int lane = threadIdx.x & 63;
    int cum = 0;
    for (int c = nbins / 64 - 1; c >= 0; --c) {
        int val = hist[c * 64 + lane];
        int s = val;                           // descending suffix-sum within chunk
        for (int d = 1; d < 64; d <<= 1) {
            int t = __shfl_down(s, d);
            if (lane + d < 64) s += t;
        }
        int total = __shfl(s, 0);
        if (cum + total >= k) {
            unsigned long long mask = __ballot(cum + s >= k);
            int bl = 63 - __builtin_clzll(mask);   // largest bin with count(>=bin) >= k
            int sB = __shfl(s, bl);
            int vB = __shfl(val, bl);
            if (lane == 0) {
                *out_bin = c * 64 + bl;
                *out_k = k - (cum + sB - vB);      // rank within selected bin
            }
            return;
        }
        cum += total;
    }
    if (lane == 0) { *out_bin = 0; *out_k = 1; }   // unreachable (k <= N guaranteed)
}

__global__ __launch_bounds__(1024) void k_select(const float* __restrict__ vneg,
                                                 const int* __restrict__ n_pos,
                                                 float* __restrict__ hard_sum,
                                                 int B, int N) {
    int b = blockIdx.x;
    const float* v = vneg + (size_t)b * N;
    __shared__ int hist[2048];
    __shared__ int bcast_bin, bcast_k;
    __shared__ float swv[16];
    __shared__ int swc[16];
    int np = n_pos[b];
    long long kk = (long long)NEG_POSK * np;
    if (kk > N) kk = N;
    int k = (int)kk;
    if (k <= 0) return;   // uniform across block
    int tid = threadIdx.x;

    // level 1: bits 30..20 (v >= 0, so float bits are order-preserving)
    for (int i = tid; i < 2048; i += 1024) hist[i] = 0;
    __syncthreads();
    for (int n = tid; n < N; n += 1024) {
        unsigned u = __float_as_uint(v[n]);
        atomicAdd(&hist[u >> 20], 1);
    }
    __syncthreads();
    if (tid < 64) wave_select(hist, 2048, k, &bcast_bin, &bcast_k);
    __syncthreads();
    int B1 = bcast_bin, k2 = bcast_k;

    // level 2: bits 19..9
    for (int i = tid; i < 2048; i += 1024) hist[i] = 0;
    __syncthreads();
    for (int n = tid; n < N; n += 1024) {
        unsigned u = __float_as_uint(v[n]);
        if ((int)(u >> 20) == B1) atomicAdd(&hist[(u >> 9) & 0x7FF], 1);
    }
    __syncthreads();
    if (tid < 64) wave_select(hist, 2048, k2, &bcast_bin, &bcast_k);
    __syncthreads();
    int B2 = bcast_bin, k3 = bcast_k;
    unsigned pre = ((unsigned)B1 << 11) | (unsigned)B2;

    // level 3: bits 8..0
    for (int i = tid; i < 512; i += 1024) hist[i] = 0;
    __syncthreads();
    for (int n = tid; n < N; n += 1024) {
        unsigned u = __float_as_uint(v[n]);
        if ((u >> 9) == pre) atomicAdd(&hist[u & 0x1FF], 1);
    }
    __syncthreads();
    if (tid < 64) wave_select(hist, 512, k3, &bcast_bin, &bcast_k);
    __syncthreads();
    unsigned tau_bits = (pre << 9) | (unsigned)bcast_bin;
    float tau = __uint_as_float(tau_bits);

    // final: hard_sum_b = sum(v > tau) + (k - count(v > tau)) * tau
    float ssum = 0.f; int scnt = 0;
    for (int n = tid; n < N; n += 1024) {
        float x = v[n];
        if (x > tau) { ssum += x; scnt++; }
    }
    for (int d = 1; d < 64; d <<= 1) {
        ssum += __shfl_xor(ssum, d);
        scnt += __shfl_xor(scnt, d);
    }
    int w = tid >> 6;
    if ((tid & 63) == 0) { swv[w] = ssum; swc[w] = scnt; }
    __syncthreads();
    if (tid == 0) {
        float S = 0.f; int Ct = 0;
        for (int i = 0; i < 16; ++i) { S += swv[i]; Ct += swc[i]; }
        float hb = S + (float)(k - Ct) * tau;
        atomicAdd(hard_sum, hb);
    }
}

// ---------------- kernel 7: finalize ---------------------------------------------
__global__ void k_final(const int* __restrict__ n_pos,
                        const float* __restrict__ loc_sum,
                        const float* __restrict__ pos_conf,
                        const float* __restrict__ hard_sum,
                        float* __restrict__ out, int B) {
    if (threadIdx.x == 0 && blockIdx.x == 0) {
        int tot = 0;
        for (int b = 0; b < B; ++b) tot += n_pos[b];
        float np = (float)tot;
        float loc = *loc_sum / (np * 4.0f);
        float conf = (*hard_sum + *pos_conf) / np;
        out[0] = 0.5f * loc + conf;   // ALPHA = 0.5
    }
}

extern "C" void kernel_launch(void* const* d_in, const int* in_sizes, int n_in,
                              void* d_out, int out_size, void* d_ws, size_t ws_size,
                              hipStream_t stream) {
    const float* locs_pred = (const float*)d_in[0];
    const float* cls_pred  = (const float*)d_in[1];
    const float* boxes     = (const float*)d_in[2];
    const int*   labels    = (const int*)d_in[3];
    const float* dboxes    = (const float*)d_in[4];

    int N = in_sizes[4] / 4;
    int B = in_sizes[0] / (4 * N);
    int O = in_sizes[3] / B;
    // C is CCLS (81) by construction of this problem.

    size_t BN = (size_t)B * N;
    char* ws = (char*)d_ws;
    int*   n_pos    = (int*)ws;                       // B ints (<= 32)
    float* loc_sum  = (float*)(ws + 128);
    float* pos_conf = (float*)(ws + 132);
    float* hard_sum = (float*)(ws + 136);
    float* best_iou = (float*)(ws + 256);             // BN f32; later reused as vneg
    int*   best_obj = (int*)(ws + 256 + BN * 4);      // BN i32
    int*   t_label  = (int*)(ws + 256 + BN * 8);      // BN i32
    int*   defbox_object = (int*)(ws + 256 + BN * 12);// B*O i32
    float* vneg = best_iou;   // alias: best_iou dead after k_label_loc

    hipMemsetAsync(ws, 0, 256, stream);

    dim3 g1((N + 255) / 256, B);
    k_anchor_best<<<g1, 256, 0, stream>>>(boxes, dboxes, best_iou, best_obj, B, N, O);
    k_object_best<<<B * O, 256, 0, stream>>>(boxes, dboxes, defbox_object, B, N, O);
    k_force<<<1, B, 0, stream>>>(defbox_object, best_iou, best_obj, B, N, O);
    k_label_loc<<<g1, 256, 0, stream>>>(boxes, dboxes, labels, locs_pred,
                                        best_iou, best_obj, t_label, n_pos, loc_sum,
                                        B, N, O);
    dim3 g5((N + TILEA - 1) / TILEA, B);
    k_conf<<<g5, 256, 0, stream>>>(cls_pred, t_label, vneg, pos_conf, B, N);
    k_select<<<B, 1024, 0, stream>>>(vneg, n_pos, hard_sum, B, N);
    k_final<<<1, 1, 0, stream>>>(n_pos, loc_sum, pos_conf, hard_sum, (float*)d_out, B);
}

// Round 2
// 534.291 us; speedup vs baseline: 1.0069x; 1.0069x over previous
//
#include <hip/hip_runtime.h>
#include <math.h>

#define THRESH    0.5f
#define NEG_POSK  3
#define EPSf      1e-6f
#define CCLS      81
#define TILEA     64

__device__ __forceinline__ float iou_xy(float ax0, float ay0, float ax1, float ay1,
                                        float bx0, float by0, float bx1, float by1) {
    float lx = fmaxf(ax0, bx0), ly = fmaxf(ay0, by0);
    float rx = fminf(ax1, bx1), ry = fminf(ay1, by1);
    float w = fmaxf(rx - lx, 0.f), h = fmaxf(ry - ly, 0.f);
    float inter = w * h;
    float aa = (ax1 - ax0) * (ay1 - ay0);
    float ab = (bx1 - bx0) * (by1 - by0);
    return inter / (aa + ab - inter);
}

// ---------------- kernel 1: per-anchor best object (argmax over O, first-max) ----
__global__ void k_anchor_best(const float* __restrict__ boxes,   // [B,O,4] xyxy
                              const float* __restrict__ dboxes,  // [N,4] cxcywh
                              float* __restrict__ best_iou, int* __restrict__ best_obj,
                              int B, int N, int O) {
    int b = blockIdx.y;
    int n = blockIdx.x * blockDim.x + threadIdx.x;
    __shared__ float sb[64];  // up to O=16 boxes * 4
    if (threadIdx.x < O * 4) sb[threadIdx.x] = boxes[(size_t)b * O * 4 + threadIdx.x];
    __syncthreads();
    if (n >= N) return;
    float4 d = ((const float4*)dboxes)[n];
    float dx0 = d.x - d.z * 0.5f, dy0 = d.y - d.w * 0.5f;
    float dx1 = d.x + d.z * 0.5f, dy1 = d.y + d.w * 0.5f;
    float best = -1.f; int bo = 0;
    for (int o = 0; o < O; ++o) {
        float iou = iou_xy(sb[o*4], sb[o*4+1], sb[o*4+2], sb[o*4+3], dx0, dy0, dx1, dy1);
        if (iou > best) { best = iou; bo = o; }   // strict > keeps first index (JAX argmax)
    }
    size_t idx = (size_t)b * N + n;
    best_iou[idx] = best;
    best_obj[idx] = bo;
}

// ---------------- kernel 2: per-object best anchor (argmax over N, first-max) ----
__global__ void k_object_best(const float* __restrict__ boxes,
                              const float* __restrict__ dboxes,
                              int* __restrict__ defbox_object,
                              int B, int N, int O) {
    int bo = blockIdx.x;
    int b = bo / O, o = bo % O;
    float ax0 = boxes[((size_t)b * O + o) * 4 + 0];
    float ay0 = boxes[((size_t)b * O + o) * 4 + 1];
    float ax1 = boxes[((size_t)b * O + o) * 4 + 2];
    float ay1 = boxes[((size_t)b * O + o) * 4 + 3];
    float best = -1.f; int bi = 0x7FFFFFFF;
    for (int n = threadIdx.x; n < N; n += blockDim.x) {
        float4 d = ((const float4*)dboxes)[n];
        float dx0 = d.x - d.z * 0.5f, dy0 = d.y - d.w * 0.5f;
        float dx1 = d.x + d.z * 0.5f, dy1 = d.y + d.w * 0.5f;
        float iou = iou_xy(ax0, ay0, ax1, ay1, dx0, dy0, dx1, dy1);
        if (iou > best) { best = iou; bi = n; }   // ascending n + strict > = first max
    }
    __shared__ float sv[256];
    __shared__ int   si[256];
    sv[threadIdx.x] = best; si[threadIdx.x] = bi;
    __syncthreads();
    for (int s = 128; s > 0; s >>= 1) {
        if (threadIdx.x < s) {
            float v2 = sv[threadIdx.x + s]; int i2 = si[threadIdx.x + s];
            if (v2 > sv[threadIdx.x] || (v2 == sv[threadIdx.x] && i2 < si[threadIdx.x])) {
                sv[threadIdx.x] = v2; si[threadIdx.x] = i2;
            }
        }
        __syncthreads();
    }
    if (threadIdx.x == 0) defbox_object[bo] = si[0];
}

// ---------------- kernel 3: forced assignment (sequential per batch, last wins) ----
__global__ void k_force(const int* __restrict__ defbox_object,
                        float* __restrict__ best_iou, int* __restrict__ best_obj,
                        int B, int N, int O) {
    int b = blockIdx.x * blockDim.x + threadIdx.x;
    if (b >= B) return;
    for (int o = 0; o < O; ++o) {
        int n = defbox_object[b * O + o];
        best_obj[(size_t)b * N + n] = o;
        best_iou[(size_t)b * N + n] = 1.0f;
    }
}

// ---------------- kernel 4: labels, pos count, smooth-L1 loc loss ----------------
__global__ void k_label_loc(const float* __restrict__ boxes,
                            const float* __restrict__ dboxes,
                            const int* __restrict__ labels,
                            const float* __restrict__ locs_pred,
                            const float* __restrict__ best_iou,
                            const int* __restrict__ best_obj,
                            int* __restrict__ t_label,
                            int* __restrict__ n_pos, float* __restrict__ loc_sum,
                            int B, int N, int O) {
    int b = blockIdx.y;
    int n = blockIdx.x * blockDim.x + threadIdx.x;
    float lsum = 0.f; int cnt = 0;
    if (n < N) {
        size_t idx = (size_t)b * N + n;
        int o = best_obj[idx];
        float iou = best_iou[idx];
        int lbl = (iou < THRESH) ? 0 : labels[b * O + o];
        t_label[idx] = lbl;
        if (lbl != 0) {
            cnt = 1;
            float bx0 = boxes[((size_t)b*O+o)*4+0], by0 = boxes[((size_t)b*O+o)*4+1];
            float bx1 = boxes[((size_t)b*O+o)*4+2], by1 = boxes[((size_t)b*O+o)*4+3];
            float bcx = (bx0 + bx1) * 0.5f, bcy = (by0 + by1) * 0.5f;
            float bw = bx1 - bx0, bh = by1 - by0;
            float4 d = ((const float4*)dboxes)[n];   // cxcywh
            float t0 = (bcx - d.x) / (d.z / 10.0f + EPSf);
            float t1 = (bcy - d.y) / (d.w / 10.0f + EPSf);
            float t2 = logf(bw / d.z + EPSf) * 5.0f;
            float t3 = logf(bh / d.w + EPSf) * 5.0f;
            float4 p = ((const float4*)locs_pred)[idx];
            float dd;
            dd = fabsf(p.x - t0); lsum += (dd < 1.f) ? 0.5f*dd*dd : dd - 0.5f;
            dd = fabsf(p.y - t1); lsum += (dd < 1.f) ? 0.5f*dd*dd : dd - 0.5f;
            dd = fabsf(p.z - t2); lsum += (dd < 1.f) ? 0.5f*dd*dd : dd - 0.5f;
            dd = fabsf(p.w - t3); lsum += (dd < 1.f) ? 0.5f*dd*dd : dd - 0.5f;
        }
    }
    for (int d = 1; d < 64; d <<= 1) {
        lsum += __shfl_xor(lsum, d);
        cnt  += __shfl_xor(cnt, d);
    }
    if ((threadIdx.x & 63) == 0) {
        if (cnt)         atomicAdd(&n_pos[b], cnt);
        if (lsum != 0.f) atomicAdd(loc_sum, lsum);
    }
}

// ---------------- kernel 5: per-anchor CE (the 254 MB streaming kernel) -----------
// Restructured: exp computed during staging (hides under global-load latency);
// read-back is a compile-time-unrolled 21-element sum per lane (ds_reads batch).
__global__ __launch_bounds__(256) void k_conf(const float* __restrict__ cls,
                                              const int* __restrict__ t_label,
                                              float* __restrict__ vneg,
                                              float* __restrict__ pos_conf,
                                              int B, int N) {
    __shared__ __align__(16) float sm[TILEA * CCLS];   // exp(x) values, 20.7 KB
    int b = blockIdx.y;
    int a0 = blockIdx.x * TILEA;
    int valid = min(TILEA, N - a0);
    int len = valid * CCLS;
    const float* g = cls + ((size_t)b * N + a0) * CCLS;   // 16B-aligned (64*81*4 % 16 == 0)
    int nvec = len >> 2;
    for (int iv = threadIdx.x; iv < nvec; iv += 256) {
        float4 v = ((const float4*)g)[iv];
        v.x = __expf(v.x); v.y = __expf(v.y);
        v.z = __expf(v.z); v.w = __expf(v.w);
        ((float4*)sm)[iv] = v;
    }
    for (int i = (nvec << 2) + threadIdx.x; i < len; i += 256) sm[i] = __expf(g[i]);
    __syncthreads();

    int a = threadIdx.x >> 2, p = threadIdx.x & 2 ? (threadIdx.x & 3) : (threadIdx.x & 3);
    p = threadIdx.x & 3;                               // 4 lanes per anchor
    bool active = (a < valid);
    const float* row = &sm[a * CCLS];
    int base = p * 20;
    float s = 0.f;
    #pragma unroll
    for (int i = 0; i < 21; ++i) {
        float e = row[base + i];                       // base+i <= 80, always in-bounds
        bool use = (i < 20) | (p == 3);                // col 80 counted once (by p==3)
        s += use ? e : 0.f;
    }
    s += __shfl_xor(s, 1);
    s += __shfl_xor(s, 2);
    float contrib = 0.f;
    if (active && p == 0) {
        int ag = a0 + a;
        int lbl = t_label[(size_t)b * N + ag];
        float conf = __logf(s) - __logf(row[lbl]);     // log(sum exp) - x[lbl]
        bool pos = (lbl != 0);
        vneg[(size_t)b * N + ag] = pos ? 0.f : conf;
        contrib = pos ? conf : 0.f;
    }
    #pragma unroll
    for (int d = 1; d < 64; d <<= 1) contrib += __shfl_xor(contrib, d);
    if ((threadIdx.x & 63) == 0 && contrib != 0.f) atomicAdd(pos_conf, contrib);
}

// ---------------- kernel 6: exact top-k sum of negatives per batch ---------------
__device__ void wave_select(const int* hist, int nbins, int k, int* out_bin, int* out_k) {
    int lane = threadIdx.x & 63;
    int cum = 0;
    for (int c = nbins / 64 - 1; c >= 0; --c) {
        int val = hist[c * 64 + lane];
        int s = val;                           // descending suffix-sum within chunk
        for (int d = 1; d < 64; d <<= 1) {
            int t = __shfl_down(s, d);
            if (lane + d < 64) s += t;
        }
        int total = __shfl(s, 0);
        if (cum + total >= k) {
            unsigned long long mask = __ballot(cum + s >= k);
            int bl = 63 - __builtin_clzll(mask);   // largest bin with count(>=bin) >= k
            int sB = __shfl(s, bl);
            int vB = __shfl(val, bl);
            if (lane == 0) {
                *out_bin = c * 64 + bl;
                *out_k = k - (cum + sB - vB);      // rank within selected bin
            }
            return;
        }
        cum += total;
    }
    if (lane == 0) { *out_bin = 0; *out_k = 1; }   // unreachable (k <= N guaranteed)
}

__global__ __launch_bounds__(1024) void k_select(const float* __restrict__ vneg,
                                                 const int* __restrict__ n_pos,
                                                 float* __restrict__ hard_sum,
                                                 int B, int N) {
    int b = blockIdx.x;
    const float* v = vneg + (size_t)b * N;
    __shared__ int hist[2048];
    __shared__ int bcast_bin, bcast_k;
    __shared__ float swv[16];
    __shared__ int swc[16];
    int np = n_pos[b];
    long long kk = (long long)NEG_POSK * np;
    if (kk > N) kk = N;
    int k = (int)kk;
    if (k <= 0) return;   // uniform across block
    int tid = threadIdx.x;

    // level 1: bits 30..20 (v >= 0, so float bits are order-preserving)
    for (int i = tid; i < 2048; i += 1024) hist[i] = 0;
    __syncthreads();
    for (int n = tid; n < N; n += 1024) {
        unsigned u = __float_as_uint(v[n]);
        atomicAdd(&hist[u >> 20], 1);
    }
    __syncthreads();
    if (tid < 64) wave_select(hist, 2048, k, &bcast_bin, &bcast_k);
    __syncthreads();
    int B1 = bcast_bin, k2 = bcast_k;

    // level 2: bits 19..9
    for (int i = tid; i < 2048; i += 1024) hist[i] = 0;
    __syncthreads();
    for (int n = tid; n < N; n += 1024) {
        unsigned u = __float_as_uint(v[n]);
        if ((int)(u >> 20) == B1) atomicAdd(&hist[(u >> 9) & 0x7FF], 1);
    }
    __syncthreads();
    if (tid < 64) wave_select(hist, 2048, k2, &bcast_bin, &bcast_k);
    __syncthreads();
    int B2 = bcast_bin, k3 = bcast_k;
    unsigned pre = ((unsigned)B1 << 11) | (unsigned)B2;

    // level 3: bits 8..0
    for (int i = tid; i < 512; i += 1024) hist[i] = 0;
    __syncthreads();
    for (int n = tid; n < N; n += 1024) {
        unsigned u = __float_as_uint(v[n]);
        if ((u >> 9) == pre) atomicAdd(&hist[u & 0x1FF], 1);
    }
    __syncthreads();
    if (tid < 64) wave_select(hist, 512, k3, &bcast_bin, &bcast_k);
    __syncthreads();
    unsigned tau_bits = (pre << 9) | (unsigned)bcast_bin;
    float tau = __uint_as_float(tau_bits);

    // final: hard_sum_b = sum(v > tau) + (k - count(v > tau)) * tau
    float ssum = 0.f; int scnt = 0;
    for (int n = tid; n < N; n += 1024) {
        float x = v[n];
        if (x > tau) { ssum += x; scnt++; }
    }
    for (int d = 1; d < 64; d <<= 1) {
        ssum += __shfl_xor(ssum, d);
        scnt += __shfl_xor(scnt, d);
    }
    int w = tid >> 6;
    if ((tid & 63) == 0) { swv[w] = ssum; swc[w] = scnt; }
    __syncthreads();
    if (tid == 0) {
        float S = 0.f; int Ct = 0;
        for (int i = 0; i < 16; ++i) { S += swv[i]; Ct += swc[i]; }
        float hb = S + (float)(k - Ct) * tau;
        atomicAdd(hard_sum, hb);
    }
}

// ---------------- kernel 7: finalize ---------------------------------------------
__global__ void k_final(const int* __restrict__ n_pos,
                        const float* __restrict__ loc_sum,
                        const float* __restrict__ pos_conf,
                        const float* __restrict__ hard_sum,
                        float* __restrict__ out, int B) {
    if (threadIdx.x == 0 && blockIdx.x == 0) {
        int tot = 0;
        for (int b = 0; b < B; ++b) tot += n_pos[b];
        float np = (float)tot;
        float loc = *loc_sum / (np * 4.0f);
        float conf = (*hard_sum + *pos_conf) / np;
        out[0] = 0.5f * loc + conf;   // ALPHA = 0.5
    }
}

extern "C" void kernel_launch(void* const* d_in, const int* in_sizes, int n_in,
                              void* d_out, int out_size, void* d_ws, size_t ws_size,
                              hipStream_t stream) {
    const float* locs_pred = (const float*)d_in[0];
    const float* cls_pred  = (const float*)d_in[1];
    const float* boxes     = (const float*)d_in[2];
    const int*   labels    = (const int*)d_in[3];
    const float* dboxes    = (const float*)d_in[4];

    int N = in_sizes[4] / 4;
    int B = in_sizes[0] / (4 * N);
    int O = in_sizes[3] / B;

    size_t BN = (size_t)B * N;
    char* ws = (char*)d_ws;
    int*   n_pos    = (int*)ws;                       // B ints (<= 32)
    float* loc_sum  = (float*)(ws + 128);
    float* pos_conf = (float*)(ws + 132);
    float* hard_sum = (float*)(ws + 136);
    float* best_iou = (float*)(ws + 256);             // BN f32; later reused as vneg
    int*   best_obj = (int*)(ws + 256 + BN * 4);      // BN i32
    int*   t_label  = (int*)(ws + 256 + BN * 8);      // BN i32
    int*   defbox_object = (int*)(ws + 256 + BN * 12);// B*O i32
    float* vneg = best_iou;   // alias: best_iou dead after k_label_loc

    hipMemsetAsync(ws, 0, 256, stream);

    dim3 g1((N + 255) / 256, B);
    k_anchor_best<<<g1, 256, 0, stream>>>(boxes, dboxes, best_iou, best_obj, B, N, O);
    k_object_best<<<B * O, 256, 0, stream>>>(boxes, dboxes, defbox_object, B, N, O);
    k_force<<<1, B, 0, stream>>>(defbox_object, best_iou, best_obj, B, N, O);
    k_label_loc<<<g1, 256, 0, stream>>>(boxes, dboxes, labels, locs_pred,
                                        best_iou, best_obj, t_label, n_pos, loc_sum,
                                        B, N, O);
    dim3 g5((N + TILEA - 1) / TILEA, B);
    k_conf<<<g5, 256, 0, stream>>>(cls_pred, t_label, vneg, pos_conf, B, N);
    k_select<<<B, 1024, 0, stream>>>(vneg, n_pos, hard_sum, B, N);
    k_final<<<1, 1, 0, stream>>>(n_pos, loc_sum, pos_conf, hard_sum, (float*)d_out, B);
}